// Round 1
// 386.914 us; speedup vs baseline: 1.0183x; 1.0183x over previous
//
#include <hip/hip_runtime.h>

// Problem constants
#define HDIM 256
#define WDIM 256
#define DDIM 64
#define HWSZ (HDIM*WDIM)          // 65536
#define NPIX 524288               // 8 * 65536

// Tiling: 32 wide x 16 tall, 512 threads, ONE pixel per thread.
#define TW 32
#define TH 16
#define BT 512
#define HW_T 38                   // TW+6
#define HH_T 22                   // TH+6
#define NPX 836                   // HW_T*HH_T halo pixels
#define DC 8                      // d-chunk size
#define NCH 8                     // 64/DC

// f16 datapath: vis tile staged in LDS as packed f16 (8 per pixel = 16 B),
// rubin chunk packed to f16x2 in registers, inner loop = 1 ds_read_b128 +
// 4 v_dot2_f32_f16 per tap (was 2 b128 + 8 fma). Halves LDS read traffic,
// which the fp32 version was bound by (~125us of ~192us). Norms stay fp32
// (computed from pre-quantization values), so only the dot is quantized.
typedef _Float16 f16;
typedef __attribute__((ext_vector_type(2))) _Float16 f16x2;

#if defined(__has_builtin)
# if __has_builtin(__builtin_amdgcn_fdot2)
#  define HAVE_FDOT2 1
# endif
#endif

__device__ __forceinline__ float fdot2(f16x2 a, f16x2 b, float c) {
#ifdef HAVE_FDOT2
    return __builtin_amdgcn_fdot2(a, b, c, false);   // v_dot2_f32_f16
#else
    return c + (float)a.x * (float)b.x + (float)a.y * (float)b.y;
#endif
}

__device__ __forceinline__ float pk2(float a, float b) {   // pack 2 fp32 -> f16x2 bits
    f16x2 t; t.x = (f16)a; t.y = (f16)b;
    return __builtin_bit_cast(float, t);
}

__device__ __forceinline__ f16x2 bc(float x) {             // reinterpret fp32 bits as f16x2
    return __builtin_bit_cast(f16x2, x);
}

// d_out layout (floats): dy, dx, conf_local, conf_global, local_weight, logits
#define OFF_DY   0
#define OFF_DX   524288
#define OFF_CONF 1048576
#define OFF_CG   1572864
#define OFF_LW   1572872
#define OFF_LG   2097160

// workspace layout (floats)
#define WS_GACC 0                 // 8*49 logit sums
#define WS_DYG  392
#define WS_DXG  400

__global__ void zero_ws_k(float* __restrict__ ws) {
    const int i = threadIdx.x;
    if (i < 408) ws[i] = 0.f;
}

__global__ void __launch_bounds__(BT, 4)
corr_main_k(const float* __restrict__ rub, const float* __restrict__ vis,
            const float* __restrict__ ltemp, float* __restrict__ out,
            float* __restrict__ ws)
{
    // 4 floats (= 8 packed f16) per halo pixel, 16 B stride: lanes 0..7 of a
    // b128 read tile all 32 banks exactly once -> conflict-free, no padding.
    __shared__ __align__(16) float vis_s[NPX * 4];       // 13376 B
    __shared__ float invv_s[NPX];                        // 3344 B
    __shared__ float gacc_s[49];

    const int tid = threadIdx.x;
    const int tx  = tid & 31;
    const int ty  = tid >> 5;                 // 0..15
    const int w0  = blockIdx.x * TW;
    const int h0  = blockIdx.y * TH;
    const int b   = blockIdx.z;
    const int ibase = b * (DDIM * HWSZ);

    if (tid < 49) gacc_s[tid] = 0.f;

    // Staging: thread covers halo px tid and tid+512 (clamped; the clamped
    // duplicate writes the same value to the same LDS slot -> benign).
    const bool val1 = (tid + BT) < NPX;
    const int px1c  = val1 ? (tid + BT) : (NPX - 1);
    auto halo_goff = [&](int px) -> int {
        const int hr = px / HW_T;
        const int wc = px - hr * HW_T;
        const int gh = min(HDIM - 1, max(0, h0 - 3 + hr));   // edge-replicate pad
        const int gw = min(WDIM - 1, max(0, w0 - 3 + wc));
        return gh * WDIM + gw;
    };
    const int goff0 = halo_goff(tid);
    const int goff1 = halo_goff(px1c);
    const int pown  = (h0 + ty) * WDIM + (w0 + tx);
    const int l0 = tid * 4;                   // float offsets into vis_s
    const int l1 = px1c * 4;

    float acc[49];
#pragma unroll
    for (int k = 0; k < 49; ++k) acc[k] = 0.f;
    float sq0 = 0.f, sq1 = 0.f, sr = 0.f;

    // Register prefetch pipeline: vv* stage chunk c's vis (packed+written to
    // LDS at top of iter c), rn holds chunk c's rubin (packed to rh at top).
    float vv0[DC], vv1[DC], rn[DC];
#pragma unroll
    for (int d = 0; d < DC; ++d) {
        const int gof = ibase + d * HWSZ;
        vv0[d] = vis[gof + goff0];
        vv1[d] = vis[gof + goff1];
        rn[d]  = rub[gof + pown];
    }

    const float* vb = vis_s + (ty * HW_T + tx) * 4;
    f16x2 rh[4];

#pragma unroll 1
    for (int c = 0; c < NCH; ++c) {
        __syncthreads();                      // WAR: prior compute done
        *reinterpret_cast<float4*>(&vis_s[l0]) =
            make_float4(pk2(vv0[0], vv0[1]), pk2(vv0[2], vv0[3]),
                        pk2(vv0[4], vv0[5]), pk2(vv0[6], vv0[7]));
        *reinterpret_cast<float4*>(&vis_s[l1]) =
            make_float4(pk2(vv1[0], vv1[1]), pk2(vv1[2], vv1[3]),
                        pk2(vv1[4], vv1[5]), pk2(vv1[6], vv1[7]));
#pragma unroll
        for (int d = 0; d < DC; ++d) { sq0 += vv0[d] * vv0[d]; sq1 += vv1[d] * vv1[d]; }
        // Pack this chunk's rubin + fp32 norm accum (before prefetch clobbers rn)
#pragma unroll
        for (int j = 0; j < 4; ++j) { f16x2 t; t.x = (f16)rn[2*j]; t.y = (f16)rn[2*j+1]; rh[j] = t; }
#pragma unroll
        for (int d = 0; d < DC; ++d) sr += rn[d] * rn[d];
        __syncthreads();                      // LDS visible

        if (c < NCH - 1) {                    // prefetch c+1 (in flight during compute)
#pragma unroll
            for (int d = 0; d < DC; ++d) {
                const int gof = ibase + ((c + 1) * DC + d) * HWSZ;
                vv0[d] = vis[gof + goff0];
                vv1[d] = vis[gof + goff1];
                rn[d]  = rub[gof + pown];
            }
        }

        // 49 ds_read_b128 + 196 v_dot2_f32_f16; offsets compile-time immediates
#pragma unroll
        for (int dyi = 0; dyi < 7; ++dyi) {
#pragma unroll
            for (int dxi = 0; dxi < 7; ++dxi) {
                const float4 v = *reinterpret_cast<const float4*>(
                    vb + (dyi * HW_T + dxi) * 4);
                float a = acc[dyi * 7 + dxi];
                a = fdot2(rh[0], bc(v.x), a);
                a = fdot2(rh[1], bc(v.y), a);
                a = fdot2(rh[2], bc(v.z), a);
                a = fdot2(rh[3], bc(v.w), a);
                acc[dyi * 7 + dxi] = a;
            }
        }
    }

    // Publish vis inverse norms for the halo (fp32, pre-quantization values)
    invv_s[tid] = 1.f / fmaxf(sqrtf(sq0), 1e-6f);
    if (val1) invv_s[tid + BT] = 1.f / fmaxf(sqrtf(sq1), 1e-6f);
    __syncthreads();

    const float tau  = fmaxf(__expf(ltemp[0]), 1e-3f);
    const float itau = 1.f / tau;
    const float invr = 1.f / fmaxf(sqrtf(sr), 1e-6f);
    const float cR   = invr * 0.125f;          // scale = 1/sqrt(64)
    const float uu   = 1.f / 49.f;
    const float i1mu = 49.f / 48.f;

    const int h = h0 + ty, w = w0 + tx;
    const int lgbase = OFF_LG + b * 49 * HWSZ + h * WDIM + w;
    float mlg = -1e30f;
#pragma unroll
    for (int dyi = 0; dyi < 7; ++dyi) {
        const int rowb = (ty + dyi) * HW_T + tx;
#pragma unroll
        for (int dxi = 0; dxi < 7; ++dxi) {
            const int k = dyi * 7 + dxi;
            const float lg = acc[k] * cR * invv_s[rowb + dxi];
            out[lgbase + k * HWSZ] = lg;
            acc[k] = lg;                       // keep logit for global reduction
            mlg = fmaxf(mlg, lg);
        }
    }
    const float m = mlg * itau;
    float S = 0.f, sdy = 0.f, sdx = 0.f;
#pragma unroll
    for (int dyi = 0; dyi < 7; ++dyi) {
#pragma unroll
        for (int dxi = 0; dxi < 7; ++dxi) {
            const float e = __expf(fmaf(acc[dyi * 7 + dxi], itau, -m));
            S += e;
            sdy += e * (float)(dyi - 3);
            sdx += e * (float)(dxi - 3);
        }
    }
    const float invS = 1.f / S;
    const float conf = invS;                   // max prob = exp(0)/S
    const float lw   = fminf(fmaxf((conf - uu) * i1mu, 0.f), 1.f);
    const int po = b * HWSZ + h * WDIM + w;
    out[OFF_CONF + po] = conf;
    out[OFF_LW   + po] = lw;
    out[OFF_DY   + po] = sdy * invS;           // local; combine_k blends with global
    out[OFF_DX   + po] = sdx * invS;

    // Global branch: wave butterfly -> LDS atomic -> one global atomic per block
#pragma unroll
    for (int k = 0; k < 49; ++k) {
        float v = acc[k];
#pragma unroll
        for (int off = 32; off > 0; off >>= 1)
            v += __shfl_xor(v, off, 64);
        if ((tid & 63) == 0) atomicAdd(&gacc_s[k], v);
    }
    __syncthreads();
    if (tid < 49) atomicAdd(&ws[WS_GACC + b * 49 + tid], gacc_s[tid]);
}

__global__ void glob_branch_k(const float* __restrict__ ltemp,
                              float* __restrict__ out, float* __restrict__ ws)
{
    const int t = threadIdx.x;
    if (t >= 8) return;
    const float tau  = fmaxf(__expf(ltemp[0]), 1e-3f);
    const float itau = 1.f / tau;
    float tk[49];
    float m = -1e30f;
#pragma unroll
    for (int k = 0; k < 49; ++k) {
        const float mean = ws[WS_GACC + t * 49 + k] * (1.f / 65536.f);
        tk[k] = mean * itau;
        m = fmaxf(m, tk[k]);
    }
    float S = 0.f, sdy = 0.f, sdx = 0.f;
#pragma unroll
    for (int k = 0; k < 49; ++k) {
        const float e = __expf(tk[k] - m);
        S += e;
        sdy += e * (float)(k / 7 - 3);
        sdx += e * (float)(k % 7 - 3);
    }
    const float invS = 1.f / S;
    out[OFF_CG + t] = invS;                  // conf_global
    ws[WS_DYG + t] = sdy * invS;
    ws[WS_DXG + t] = sdx * invS;
}

__global__ void combine_k(float* __restrict__ out, const float* __restrict__ ws)
{
    const int gid = blockIdx.x * 256 + threadIdx.x;
    if (gid >= NPIX) return;
    const int b = gid >> 16;
    const float lw  = out[OFF_LW + gid];
    const float dyl = out[OFF_DY + gid];
    const float dxl = out[OFF_DX + gid];
    out[OFF_DY + gid] = lw * dyl + (1.f - lw) * ws[WS_DYG + b];
    out[OFF_DX + gid] = lw * dxl + (1.f - lw) * ws[WS_DXG + b];
}

extern "C" void kernel_launch(void* const* d_in, const int* in_sizes, int n_in,
                              void* d_out, int out_size, void* d_ws, size_t ws_size,
                              hipStream_t stream)
{
    const float* rub = (const float*)d_in[0];
    const float* vis = (const float*)d_in[1];
    const float* lt  = (const float*)d_in[2];
    float* out = (float*)d_out;
    float* ws  = (float*)d_ws;

    hipLaunchKernelGGL(zero_ws_k, dim3(1), dim3(512), 0, stream, ws);
    hipLaunchKernelGGL(corr_main_k, dim3(WDIM / TW, HDIM / TH, 8), dim3(BT), 0, stream,
                       rub, vis, lt, out, ws);
    hipLaunchKernelGGL(glob_branch_k, dim3(1), dim3(64), 0, stream, lt, out, ws);
    hipLaunchKernelGGL(combine_k, dim3(NPIX / 256), dim3(256), 0, stream, out, ws);
}